// Round 7
// baseline (202.781 us; speedup 1.0000x reference)
//
#include <hip/hip_runtime.h>
#include <math.h>

#define L 2048
#define B 8
#define D 1024
#define ND 16
#define BD (B*D)
#define CKC 64               // chunk length
#define NCC (L/CKC)          // 32 chunks
#define CHB 128              // channels per block
#define NWG ((D/CHB)*B*NCC)  // 8*8*32 = 2048 workgroups (multiple of 8)

__device__ __forceinline__ float sigmoid_precise(float v) {
    return 1.0f / (1.0f + expf(-v));
}
// fast sigmoid: v_exp + v_rcp (~3e-7 rel err; tolerance is 0.0625 abs)
__device__ __forceinline__ float sigmoid_fast(float v) {
    return __builtin_amdgcn_rcpf(1.0f + __expf(-v));
}

// Chunked XCD swizzle (bijective since NWG % 8 == 0): hardware dispatch index
// round-robins XCDs, so give each XCD a CONTIGUOUS logical range. All 8
// dblk-blocks of one (b,ch) then share an XCD/L2 -> dense row-span fetches.
__device__ __forceinline__ int xcd_chunked(int orig) {
    return (orig & 7) * (NWG / 8) + (orig >> 3);
}

// Per-mode decay q[16] for row `row` (row-major params: [2D][ND]).
__device__ __forceinline__ void load_q(const float* __restrict__ damp,
                                       const float* __restrict__ decay,
                                       int row, float* q) {
#pragma unroll
    for (int mg = 0; mg < 4; ++mg) {
        const float4 dp = reinterpret_cast<const float4*>(damp)[row * 4 + mg];
        const float4 dc = reinterpret_cast<const float4*>(decay)[row * 4 + mg];
        q[4*mg+0] = 1.f - sigmoid_fast(dp.x) * sigmoid_fast(dc.x);
        q[4*mg+1] = 1.f - sigmoid_fast(dp.y) * sigmoid_fast(dc.y);
        q[4*mg+2] = 1.f - sigmoid_fast(dp.z) * sigmoid_fast(dc.z);
        q[4*mg+3] = 1.f - sigmoid_fast(dp.w) * sigmoid_fast(dc.w);
    }
}

// Per-mode decay q[16] and output coefficient c[16] (= p * ema * proj / sqrt(ND)).
__device__ __forceinline__ void load_qc(const float* __restrict__ damp,
                                        const float* __restrict__ decay,
                                        const float* __restrict__ ema,
                                        const float* __restrict__ proj,
                                        int row, float* q, float* c) {
#pragma unroll
    for (int mg = 0; mg < 4; ++mg) {
        const float4 dp = reinterpret_cast<const float4*>(damp)[row * 4 + mg];
        const float4 dc = reinterpret_cast<const float4*>(decay)[row * 4 + mg];
        const float4 em = reinterpret_cast<const float4*>(ema)[row * 4 + mg];
        const float4 pj = reinterpret_cast<const float4*>(proj)[row * 4 + mg];
        const float p0 = sigmoid_fast(dp.x), p1 = sigmoid_fast(dp.y),
                    p2 = sigmoid_fast(dp.z), p3 = sigmoid_fast(dp.w);
        q[4*mg+0] = 1.f - p0 * sigmoid_fast(dc.x);
        q[4*mg+1] = 1.f - p1 * sigmoid_fast(dc.y);
        q[4*mg+2] = 1.f - p2 * sigmoid_fast(dc.z);
        q[4*mg+3] = 1.f - p3 * sigmoid_fast(dc.w);
        c[4*mg+0] = p0 * em.x * pj.x * 0.25f;
        c[4*mg+1] = p1 * em.y * pj.y * 0.25f;
        c[4*mg+2] = p2 * em.z * pj.z * 0.25f;
        c[4*mg+3] = p3 * em.w * pj.w * 0.25f;
    }
}

// ---------------- Phase A: per-chunk local states (both directions) ----------
// Block = 256 threads over 128 consecutive channels: waves 0-1 = fwd halves,
// waves 2-3 = bwd halves (u = i ^ um). Per j the block touches 512B/dir
// contiguous. 16-deep prefetch, outer loop NOT unrolled (bounded liveness).
__global__ __launch_bounds__(256, 2) void ema_summary_kernel(
    const float* __restrict__ x, const float* __restrict__ damp,
    const float* __restrict__ decay, const int* __restrict__ mask,
    float* __restrict__ fwdS, float* __restrict__ bwdS)
{
    const int lg   = xcd_chunked(blockIdx.x);
    const int dblk = lg & (D / CHB - 1);
    const int b    = (lg >> 3) & (B - 1);
    const int ch   = lg >> 6;

    const int tid    = threadIdx.x;
    const int lane   = tid & 63;
    const int wid    = tid >> 6;            // 0..3
    const int dir    = wid >> 1;            // 0 = fwd, 1 = bwd
    const int lane_ch = (wid & 1) * 64 + lane;
    const int d  = dblk * CHB + lane_ch;
    const int j0 = ch * CKC;
    const int um = dir ? (CKC - 1) : 0;     // u = i ^ um

    const float* xp = x + (size_t)j0 * BD + (size_t)b * D + d;
    const int*   mp = mask + (size_t)b * L + j0;       // wave-uniform
    const int row = dir ? (d + D) : d;

    float q[ND], st[ND];
    load_q(damp, decay, row, q);
#pragma unroll
    for (int k = 0; k < ND; ++k) st[k] = 0.f;

#pragma unroll 1
    for (int g = 0; g < CKC; g += 16) {
        float xr[16], mf[16];
#pragma unroll
        for (int v = 0; v < 16; ++v) {
            const int u = (g + v) ^ um;
            xr[v] = xp[(size_t)u * BD];
            mf[v] = (float)mp[u];
        }
#pragma unroll
        for (int v = 0; v < 16; ++v) {
            const float xm = xr[v] * mf[v];
#pragma unroll
            for (int k = 0; k < ND; ++k) st[k] = fmaf(q[k], st[k], xm);
        }
    }
    float* Sx = dir ? bwdS : fwdS;
    float4* s4 = reinterpret_cast<float4*>(Sx) + ((size_t)(b * NCC + ch) * D + d) * 4;
#pragma unroll
    for (int mg = 0; mg < 4; ++mg)
        s4[mg] = make_float4(st[4*mg+0], st[4*mg+1], st[4*mg+2], st[4*mg+3]);
}

// ---------------- Phase B: prefix across chunks (in-place -> entry states) ---
// One thread per (b, d, mode). All chunk values prefetched, then the two
// serial fma chains (fwd + bwd) interleaved for 2x chain ILP.
__global__ __launch_bounds__(256) void ema_prefix_kernel(
    const float* __restrict__ damp, const float* __restrict__ decay,
    float* __restrict__ fwdS, float* __restrict__ bwdS)
{
    constexpr int NC = NCC;
    const int tid = blockIdx.x * 256 + threadIdx.x;
    const int m = tid & (ND - 1);
    const int d = (tid >> 4) & (D - 1);
    const int b = tid >> 14;
    const size_t CS = (size_t)D * ND;   // stride between chunks
    const size_t off = (size_t)b * NC * CS + (size_t)d * ND + m;
    float* fb = fwdS + off;
    float* bb = bwdS + off;

    const int idxf = d * ND + m;
    const int idxb = (d + D) * ND + m;
    float qf = 1.f - sigmoid_fast(damp[idxf]) * sigmoid_fast(decay[idxf]);
    float qb = 1.f - sigmoid_fast(damp[idxb]) * sigmoid_fast(decay[idxb]);
#pragma unroll
    for (int s = 0; s < 6; ++s) { qf *= qf; qb *= qb; }   // q^64

    float Ef[NC], Eb[NC];
#pragma unroll
    for (int i = 0; i < NC; ++i) Ef[i] = fb[(size_t)i * CS];
#pragma unroll
    for (int i = 0; i < NC; ++i) Eb[i] = bb[(size_t)i * CS];

    float F = 0.f, G = 0.f;
#pragma unroll
    for (int i = 0; i < NC; ++i) {
        fb[(size_t)i * CS] = F;               F = fmaf(qf, F, Ef[i]);
        bb[(size_t)(NC-1-i) * CS] = G;        G = fmaf(qb, G, Eb[NC-1-i]);
    }
}

// ---------------- Phase C: apply (both directions + residual + silu) ---------
// Block = 256 threads / 128 channels; waves 0-1 causal, waves 2-3 anti-causal.
// Half-LDS exchange: phase 1 (first 32 scan steps) -> hacc[dir][u&31][ch];
// one __syncthreads; phase 2 continues the scan, combines with the other
// direction's LDS slot, silu, direct coalesced store. 16-deep prefetch,
// no register arrays, outer loops not unrolled.
__global__ __launch_bounds__(256, 2) void ema_apply_kernel(
    const float* __restrict__ x, const float* __restrict__ damp,
    const float* __restrict__ decay, const float* __restrict__ ema,
    const float* __restrict__ proj, const float* __restrict__ rw,
    const int* __restrict__ mask,
    const float* __restrict__ fwdS, const float* __restrict__ bwdS,
    float* __restrict__ out)
{
    constexpr int HALF = CKC / 2;
    __shared__ float hacc[2][HALF][CHB];     // 32 KB

    const int lg   = xcd_chunked(blockIdx.x);
    const int dblk = lg & (D / CHB - 1);
    const int b    = (lg >> 3) & (B - 1);
    const int ch   = lg >> 6;

    const int tid    = threadIdx.x;
    const int lane   = tid & 63;
    const int wid    = tid >> 6;            // 0..3
    const int dir    = wid >> 1;            // 0 = fwd, 1 = bwd
    const int lane_ch = (wid & 1) * 64 + lane;
    const int d  = dblk * CHB + lane_ch;
    const int j0 = ch * CKC;
    const int um = dir ? (CKC - 1) : 0;     // u = i ^ um

    const float* xp = x   + (size_t)j0 * BD + (size_t)b * D + d;
    float*       op = out + (size_t)j0 * BD + (size_t)b * D + d;
    const int*   mp = mask + (size_t)b * L + j0;     // wave-uniform
    const int    row  = dir ? (d + D) : d;
    const float  weff = dir ? 0.f : rw[d];           // residual only on fwd
    const float* Sx   = dir ? bwdS : fwdS;

    float q[ND], c[ND], st[ND];
    load_qc(damp, decay, ema, proj, row, q, c);
    {
        const float4* s4 = reinterpret_cast<const float4*>(Sx) + ((size_t)(b * NCC + ch) * D + d) * 4;
#pragma unroll
        for (int mg = 0; mg < 4; ++mg) {
            const float4 v = s4[mg];
            st[4*mg+0] = v.x; st[4*mg+1] = v.y; st[4*mg+2] = v.z; st[4*mg+3] = v.w;
        }
    }

    // ---- phase 1: first half of this direction's scan -> LDS ----
#pragma unroll 1
    for (int g = 0; g < HALF; g += 16) {
        float xr[16], mf[16];
#pragma unroll
        for (int v = 0; v < 16; ++v) {
            const int u = (g + v) ^ um;
            xr[v] = xp[(size_t)u * BD];
            mf[v] = (float)mp[u];
        }
#pragma unroll
        for (int v = 0; v < 16; ++v) {
            const int u = (g + v) ^ um;
            const float xraw = xr[v];
            const float xm   = xraw * mf[v];
#pragma unroll
            for (int k = 0; k < ND; ++k) st[k] = fmaf(q[k], st[k], xm);
            float a0 = c[0] * st[0], a1 = c[1] * st[1],
                  a2 = c[2] * st[2], a3 = c[3] * st[3];
#pragma unroll
            for (int k = 4; k < ND; k += 4) {
                a0 = fmaf(c[k+0], st[k+0], a0);
                a1 = fmaf(c[k+1], st[k+1], a1);
                a2 = fmaf(c[k+2], st[k+2], a2);
                a3 = fmaf(c[k+3], st[k+3], a3);
            }
            hacc[dir][u & (HALF - 1)][lane_ch] = fmaf(xraw, weff, (a0 + a1) + (a2 + a3));
        }
    }
    __syncthreads();

    // ---- phase 2: second half of scan + combine with other direction ----
    const int od = 1 - dir;
#pragma unroll 1
    for (int g = HALF; g < CKC; g += 16) {
        float xr[16], mf[16];
#pragma unroll
        for (int v = 0; v < 16; ++v) {
            const int u = (g + v) ^ um;
            xr[v] = xp[(size_t)u * BD];
            mf[v] = (float)mp[u];
        }
#pragma unroll
        for (int v = 0; v < 16; ++v) {
            const int u = (g + v) ^ um;
            const float xraw = xr[v];
            const float xm   = xraw * mf[v];
#pragma unroll
            for (int k = 0; k < ND; ++k) st[k] = fmaf(q[k], st[k], xm);
            float a0 = c[0] * st[0], a1 = c[1] * st[1],
                  a2 = c[2] * st[2], a3 = c[3] * st[3];
#pragma unroll
            for (int k = 4; k < ND; k += 4) {
                a0 = fmaf(c[k+0], st[k+0], a0);
                a1 = fmaf(c[k+1], st[k+1], a1);
                a2 = fmaf(c[k+2], st[k+2], a2);
                a3 = fmaf(c[k+3], st[k+3], a3);
            }
            const float tv  = fmaf(xraw, weff, (a0 + a1) + (a2 + a3));
            const float val = tv + hacc[od][u & (HALF - 1)][lane_ch];
            // fast silu: val * rcp(1 + exp(-val))
            op[(size_t)u * BD] = val * __builtin_amdgcn_rcpf(1.0f + __expf(-val));
        }
    }
}

// ---------------- Fallback: validated single-pass scans ----------------------
template<int DIR>
__device__ __forceinline__ void ema_scan_body(
    const float* __restrict__ x, const float* __restrict__ damp,
    const float* __restrict__ decay, const float* __restrict__ ema,
    const float* __restrict__ proj, const float* __restrict__ rw,
    const int* __restrict__ mask, float* __restrict__ out)
{
    const int t  = threadIdx.x;
    const int ng = t & 3;
    const int dl = t >> 2;
    const int d  = blockIdx.x * 16 + dl;
    const int b  = blockIdx.y;
    const int row = (DIR == 0) ? d : (d + D);

    float q[4], c[4];
#pragma unroll
    for (int k = 0; k < 4; ++k) {
        const int idx = row * ND + ng * 4 + k;
        const float p  = sigmoid_precise(damp[idx]);
        const float sd = sigmoid_precise(decay[idx]);
        q[k] = 1.0f - p * sd;
        c[k] = p * ema[idx] * proj[idx] * 0.25f;
    }
    const float w = rw[d];
    const float* xp = x + (size_t)b * D + d;
    float*       op = out + (size_t)b * D + d;
    const int*   mp = mask + (size_t)b * L;
    float s0 = 0.f, s1 = 0.f, s2 = 0.f, s3 = 0.f;

    for (int jj = 0; jj < L; jj += 4) {
        float xv[4], mf[4];
#pragma unroll
        for (int u = 0; u < 4; ++u) {
            const int j = (DIR == 0) ? (jj + u) : (L - 1 - (jj + u));
            xv[u] = xp[(size_t)j * BD];
            mf[u] = (float)mp[j];
        }
        float acc[4];
#pragma unroll
        for (int u = 0; u < 4; ++u) {
            const float xm = xv[u] * mf[u];
            s0 = fmaf(q[0], s0, xm);
            s1 = fmaf(q[1], s1, xm);
            s2 = fmaf(q[2], s2, xm);
            s3 = fmaf(q[3], s3, xm);
            acc[u] = fmaf(c[1], s1, c[0] * s0) + fmaf(c[3], s3, c[2] * s2);
        }
#pragma unroll
        for (int u = 0; u < 4; ++u) acc[u] += __shfl_xor(acc[u], 1);
#pragma unroll
        for (int u = 0; u < 4; ++u) acc[u] += __shfl_xor(acc[u], 2);
        if (ng == 0) {
#pragma unroll
            for (int u = 0; u < 4; ++u) {
                const int j = (DIR == 0) ? (jj + u) : (L - 1 - (jj + u));
                const size_t oi = (size_t)j * BD;
                if (DIR == 0) op[oi] = fmaf(xv[u], w, acc[u]);
                else { const float v = op[oi] + acc[u]; op[oi] = v / (1.0f + expf(-v)); }
            }
        }
    }
}

__global__ __launch_bounds__(64) void ema_fwd_kernel(
    const float* __restrict__ x, const float* __restrict__ damp,
    const float* __restrict__ decay, const float* __restrict__ ema,
    const float* __restrict__ proj, const float* __restrict__ rw,
    const int* __restrict__ mask, float* __restrict__ out)
{ ema_scan_body<0>(x, damp, decay, ema, proj, rw, mask, out); }

__global__ __launch_bounds__(64) void ema_bwd_kernel(
    const float* __restrict__ x, const float* __restrict__ damp,
    const float* __restrict__ decay, const float* __restrict__ ema,
    const float* __restrict__ proj, const float* __restrict__ rw,
    const int* __restrict__ mask, float* __restrict__ out)
{ ema_scan_body<1>(x, damp, decay, ema, proj, rw, mask, out); }

// ---------------- driver -----------------------------------------------------
extern "C" void kernel_launch(void* const* d_in, const int* in_sizes, int n_in,
                              void* d_out, int out_size, void* d_ws, size_t ws_size,
                              hipStream_t stream) {
    (void)in_sizes; (void)n_in; (void)out_size;
    const float* x     = (const float*)d_in[0];
    const float* damp  = (const float*)d_in[1];
    const float* decay = (const float*)d_in[2];
    const float* ema   = (const float*)d_in[3];
    const float* proj  = (const float*)d_in[4];
    const float* rw    = (const float*)d_in[5];
    const int*   mask  = (const int*)d_in[6];
    float* out = (float*)d_out;

    const size_t need = (size_t)2 * B * NCC * D * ND * sizeof(float);  // 33.6 MB

    if (ws_size >= need) {
        float* fwdS = (float*)d_ws;
        float* bwdS = fwdS + (size_t)B * NCC * D * ND;
        ema_summary_kernel<<<dim3(NWG), dim3(256), 0, stream>>>(x, damp, decay, mask, fwdS, bwdS);
        ema_prefix_kernel<<<dim3((B * D * ND) / 256), dim3(256), 0, stream>>>(damp, decay, fwdS, bwdS);
        ema_apply_kernel<<<dim3(NWG), dim3(256), 0, stream>>>(x, damp, decay, ema, proj, rw, mask,
                                                              fwdS, bwdS, out);
    } else {
        dim3 grid(D / 16, B);
        dim3 block(64);
        ema_fwd_kernel<<<grid, block, 0, stream>>>(x, damp, decay, ema, proj, rw, mask, out);
        ema_bwd_kernel<<<grid, block, 0, stream>>>(x, damp, decay, ema, proj, rw, mask, out);
    }
}

// Round 8
// 188.240 us; speedup vs baseline: 1.0772x; 1.0772x over previous
//
#include <hip/hip_runtime.h>
#include <math.h>

#define L 2048
#define B 8
#define D 1024
#define ND 16
#define BD (B*D)
#define CK 64                // chunk length
#define NC (L/CK)            // 32 chunks

__device__ __forceinline__ float sigmoid_precise(float v) {
    return 1.0f / (1.0f + expf(-v));
}
// fast sigmoid: v_exp + v_rcp (~3e-7 rel err; tolerance is 0.0625 abs)
__device__ __forceinline__ float sigmoid_fast(float v) {
    return __builtin_amdgcn_rcpf(1.0f + __expf(-v));
}

// Per-mode decay q[16] for row `row` (row-major params: [2D][ND]).
__device__ __forceinline__ void load_q(const float* __restrict__ damp,
                                       const float* __restrict__ decay,
                                       int row, float* q) {
#pragma unroll
    for (int mg = 0; mg < 4; ++mg) {
        const float4 dp = reinterpret_cast<const float4*>(damp)[row * 4 + mg];
        const float4 dc = reinterpret_cast<const float4*>(decay)[row * 4 + mg];
        q[4*mg+0] = 1.f - sigmoid_fast(dp.x) * sigmoid_fast(dc.x);
        q[4*mg+1] = 1.f - sigmoid_fast(dp.y) * sigmoid_fast(dc.y);
        q[4*mg+2] = 1.f - sigmoid_fast(dp.z) * sigmoid_fast(dc.z);
        q[4*mg+3] = 1.f - sigmoid_fast(dp.w) * sigmoid_fast(dc.w);
    }
}

// Per-mode decay q[16] and output coefficient c[16] (= p * ema * proj / sqrt(ND)).
__device__ __forceinline__ void load_qc(const float* __restrict__ damp,
                                        const float* __restrict__ decay,
                                        const float* __restrict__ ema,
                                        const float* __restrict__ proj,
                                        int row, float* q, float* c) {
#pragma unroll
    for (int mg = 0; mg < 4; ++mg) {
        const float4 dp = reinterpret_cast<const float4*>(damp)[row * 4 + mg];
        const float4 dc = reinterpret_cast<const float4*>(decay)[row * 4 + mg];
        const float4 em = reinterpret_cast<const float4*>(ema)[row * 4 + mg];
        const float4 pj = reinterpret_cast<const float4*>(proj)[row * 4 + mg];
        const float p0 = sigmoid_fast(dp.x), p1 = sigmoid_fast(dp.y),
                    p2 = sigmoid_fast(dp.z), p3 = sigmoid_fast(dp.w);
        q[4*mg+0] = 1.f - p0 * sigmoid_fast(dc.x);
        q[4*mg+1] = 1.f - p1 * sigmoid_fast(dc.y);
        q[4*mg+2] = 1.f - p2 * sigmoid_fast(dc.z);
        q[4*mg+3] = 1.f - p3 * sigmoid_fast(dc.w);
        c[4*mg+0] = p0 * em.x * pj.x * 0.25f;
        c[4*mg+1] = p1 * em.y * pj.y * 0.25f;
        c[4*mg+2] = p2 * em.z * pj.z * 0.25f;
        c[4*mg+3] = p3 * em.w * pj.w * 0.25f;
    }
}

// ---------------- Phase A: per-chunk local states (both directions) ----------
// Block = 128 threads: wave 0 scans forward (u = i), wave 1 backward
// (u = i ^ (CK-1)). Software-pipelined 3-buffer prefetch (fully flattened,
// static register indexing only). Masks staged to LDS once per block so x
// loads own the whole vmcnt budget.
__global__ __launch_bounds__(128, 2) void ema_summary_kernel(
    const float* __restrict__ x, const float* __restrict__ damp,
    const float* __restrict__ decay, const int* __restrict__ mask,
    float* __restrict__ fwdS, float* __restrict__ bwdS)
{
    __shared__ float smask[CK];
    const int lane = threadIdx.x & 63;
    const int wid  = threadIdx.x >> 6;          // 0 = fwd, 1 = bwd
    const int d  = blockIdx.x * 64 + lane;
    const int b  = blockIdx.y;
    const int ch = blockIdx.z;
    const int j0 = ch * CK;
    const int um = wid ? (CK - 1) : 0;          // u = i ^ um

    const float* xp = x + (size_t)j0 * BD + (size_t)b * D + d;
    const int*   mp = mask + (size_t)b * L + j0;
    if (threadIdx.x < CK) smask[threadIdx.x] = (float)mp[threadIdx.x];
    __syncthreads();

    const int row = wid ? (d + D) : d;
    float q[ND], st[ND];
    load_q(damp, decay, row, q);
#pragma unroll
    for (int k = 0; k < ND; ++k) st[k] = 0.f;

    float xA[16], xB[16], xC[16];

#define SLOADG(XR, G) \
    _Pragma("unroll") \
    for (int v = 0; v < 16; ++v) { \
        const int u = ((G) + v) ^ um; \
        XR[v] = xp[(size_t)u * BD]; \
    }
#define SCOMPG(XR, G) \
    _Pragma("unroll") \
    for (int v = 0; v < 16; ++v) { \
        const int u = ((G) + v) ^ um; \
        const float xm = XR[v] * smask[u]; \
        _Pragma("unroll") \
        for (int k = 0; k < ND; ++k) st[k] = fmaf(q[k], st[k], xm); \
    }

    SLOADG(xA, 0)
    SLOADG(xB, 16)
    SLOADG(xC, 32)
    SCOMPG(xA, 0)
    SLOADG(xA, 48)
    SCOMPG(xB, 16)
    SCOMPG(xC, 32)
    SCOMPG(xA, 48)
#undef SLOADG
#undef SCOMPG

    float* Sx = wid ? bwdS : fwdS;
    float4* s4 = reinterpret_cast<float4*>(Sx) + ((size_t)(b * NC + ch) * D + d) * 4;
#pragma unroll
    for (int mg = 0; mg < 4; ++mg)
        s4[mg] = make_float4(st[4*mg+0], st[4*mg+1], st[4*mg+2], st[4*mg+3]);
}

// ---------------- Phase B: prefix across chunks (in-place -> entry states) ---
// One thread per (b, d, mode). All chunk values prefetched, then the two
// serial fma chains (fwd + bwd) interleaved for 2x chain ILP.
__global__ __launch_bounds__(256) void ema_prefix_kernel(
    const float* __restrict__ damp, const float* __restrict__ decay,
    float* __restrict__ fwdS, float* __restrict__ bwdS)
{
    const int tid = blockIdx.x * 256 + threadIdx.x;
    const int m = tid & (ND - 1);
    const int d = (tid >> 4) & (D - 1);
    const int b = tid >> 14;
    const size_t CS = (size_t)D * ND;   // stride between chunks
    const size_t off = (size_t)b * NC * CS + (size_t)d * ND + m;
    float* fb = fwdS + off;
    float* bb = bwdS + off;

    const int idxf = d * ND + m;
    const int idxb = (d + D) * ND + m;
    float qf = 1.f - sigmoid_fast(damp[idxf]) * sigmoid_fast(decay[idxf]);
    float qb = 1.f - sigmoid_fast(damp[idxb]) * sigmoid_fast(decay[idxb]);
#pragma unroll
    for (int s = 0; s < 6; ++s) { qf *= qf; qb *= qb; }   // q^64

    float Ef[NC], Eb[NC];
#pragma unroll
    for (int i = 0; i < NC; ++i) Ef[i] = fb[(size_t)i * CS];
#pragma unroll
    for (int i = 0; i < NC; ++i) Eb[i] = bb[(size_t)i * CS];

    float F = 0.f, G = 0.f;
#pragma unroll
    for (int i = 0; i < NC; ++i) {
        fb[(size_t)i * CS] = F;               F = fmaf(qf, F, Ef[i]);
        bb[(size_t)(NC-1-i) * CS] = G;        G = fmaf(qb, G, Eb[NC-1-i]);
    }
}

// ---------------- Phase C: apply (both directions + residual + silu) ---------
// Round-6 half-LDS exchange + software-pipelined 3-buffer prefetch.
// Wave 0 causal (u = i), wave 1 anti-causal (u = i^63). Phase 1 (first 32
// scan steps) -> hacc[wid][u&31][lane]; phase-2 x loads are issued BEFORE the
// barrier; after __syncthreads each wave finishes its scan, combines with the
// other wave's LDS half, silu, coalesced store.
__global__ __launch_bounds__(128, 2) void ema_apply_kernel(
    const float* __restrict__ x, const float* __restrict__ damp,
    const float* __restrict__ decay, const float* __restrict__ ema,
    const float* __restrict__ proj, const float* __restrict__ rw,
    const int* __restrict__ mask,
    const float* __restrict__ fwdS, const float* __restrict__ bwdS,
    float* __restrict__ out)
{
    constexpr int HALF = CK / 2;
    __shared__ float hacc[2][HALF][64];      // 16 KB
    __shared__ float smask[CK];

    const int lane = threadIdx.x & 63;
    const int wid  = threadIdx.x >> 6;       // 0 = fwd, 1 = bwd
    const int d  = blockIdx.x * 64 + lane;
    const int b  = blockIdx.y;
    const int ch = blockIdx.z;
    const int j0 = ch * CK;
    const int um = wid ? (CK - 1) : 0;       // u = i ^ um

    const float* xp = x   + (size_t)j0 * BD + (size_t)b * D + d;
    float*       op = out + (size_t)j0 * BD + (size_t)b * D + d;
    const int*   mp = mask + (size_t)b * L + j0;
    if (threadIdx.x < CK) smask[threadIdx.x] = (float)mp[threadIdx.x];

    const int    row  = wid ? (d + D) : d;
    const float  weff = wid ? 0.f : rw[d];           // residual only on fwd wave
    const float* Sx   = wid ? bwdS : fwdS;

    float q[ND], c[ND], st[ND];
    load_qc(damp, decay, ema, proj, row, q, c);
    {
        const float4* s4 = reinterpret_cast<const float4*>(Sx) + ((size_t)(b * NC + ch) * D + d) * 4;
#pragma unroll
        for (int mg = 0; mg < 4; ++mg) {
            const float4 v = s4[mg];
            st[4*mg+0] = v.x; st[4*mg+1] = v.y; st[4*mg+2] = v.z; st[4*mg+3] = v.w;
        }
    }
    __syncthreads();   // smask visible

    float xA[16], xB[16], xC[16];

#define ALOADG(XR, G) \
    _Pragma("unroll") \
    for (int v = 0; v < 16; ++v) { \
        const int u = ((G) + v) ^ um; \
        XR[v] = xp[(size_t)u * BD]; \
    }
#define ADOT(a0, a1, a2, a3) \
    float a0 = c[0] * st[0], a1 = c[1] * st[1], \
          a2 = c[2] * st[2], a3 = c[3] * st[3]; \
    _Pragma("unroll") \
    for (int k = 4; k < ND; k += 4) { \
        a0 = fmaf(c[k+0], st[k+0], a0); \
        a1 = fmaf(c[k+1], st[k+1], a1); \
        a2 = fmaf(c[k+2], st[k+2], a2); \
        a3 = fmaf(c[k+3], st[k+3], a3); \
    }
#define ACOMP_LDS(XR, G) \
    _Pragma("unroll") \
    for (int v = 0; v < 16; ++v) { \
        const int u = ((G) + v) ^ um; \
        const float xraw = XR[v]; \
        const float xm   = xraw * smask[u]; \
        _Pragma("unroll") \
        for (int k = 0; k < ND; ++k) st[k] = fmaf(q[k], st[k], xm); \
        ADOT(a0, a1, a2, a3) \
        hacc[wid][u & (HALF - 1)][lane] = fmaf(xraw, weff, (a0 + a1) + (a2 + a3)); \
    }
#define ACOMP_OUT(XR, G) \
    _Pragma("unroll") \
    for (int v = 0; v < 16; ++v) { \
        const int u = ((G) + v) ^ um; \
        const float xraw = XR[v]; \
        const float xm   = xraw * smask[u]; \
        _Pragma("unroll") \
        for (int k = 0; k < ND; ++k) st[k] = fmaf(q[k], st[k], xm); \
        ADOT(a0, a1, a2, a3) \
        const float tv  = fmaf(xraw, weff, (a0 + a1) + (a2 + a3)); \
        const float val = tv + hacc[ow][u & (HALF - 1)][lane]; \
        op[(size_t)u * BD] = val * __builtin_amdgcn_rcpf(1.0f + __expf(-val)); \
    }

    // phase 1 (scan steps 0..31 -> LDS), with phase-2 loads already in flight
    ALOADG(xA, 0)
    ALOADG(xB, 16)
    ALOADG(xC, 32)
    ACOMP_LDS(xA, 0)
    ALOADG(xA, 48)
    ACOMP_LDS(xB, 16)
    __syncthreads();

    // phase 2 (scan steps 32..63): combine with other wave's half, silu, store
    const int ow = 1 - wid;
    ACOMP_OUT(xC, 32)
    ACOMP_OUT(xA, 48)
#undef ALOADG
#undef ADOT
#undef ACOMP_LDS
#undef ACOMP_OUT
}

// ---------------- Fallback: validated single-pass scans ----------------------
template<int DIR>
__device__ __forceinline__ void ema_scan_body(
    const float* __restrict__ x, const float* __restrict__ damp,
    const float* __restrict__ decay, const float* __restrict__ ema,
    const float* __restrict__ proj, const float* __restrict__ rw,
    const int* __restrict__ mask, float* __restrict__ out)
{
    const int t  = threadIdx.x;
    const int ng = t & 3;
    const int dl = t >> 2;
    const int d  = blockIdx.x * 16 + dl;
    const int b  = blockIdx.y;
    const int row = (DIR == 0) ? d : (d + D);

    float q[4], c[4];
#pragma unroll
    for (int k = 0; k < 4; ++k) {
        const int idx = row * ND + ng * 4 + k;
        const float p  = sigmoid_precise(damp[idx]);
        const float sd = sigmoid_precise(decay[idx]);
        q[k] = 1.0f - p * sd;
        c[k] = p * ema[idx] * proj[idx] * 0.25f;
    }
    const float w = rw[d];
    const float* xp = x + (size_t)b * D + d;
    float*       op = out + (size_t)b * D + d;
    const int*   mp = mask + (size_t)b * L;
    float s0 = 0.f, s1 = 0.f, s2 = 0.f, s3 = 0.f;

    for (int jj = 0; jj < L; jj += 4) {
        float xv[4], mf[4];
#pragma unroll
        for (int u = 0; u < 4; ++u) {
            const int j = (DIR == 0) ? (jj + u) : (L - 1 - (jj + u));
            xv[u] = xp[(size_t)j * BD];
            mf[u] = (float)mp[j];
        }
        float acc[4];
#pragma unroll
        for (int u = 0; u < 4; ++u) {
            const float xm = xv[u] * mf[u];
            s0 = fmaf(q[0], s0, xm);
            s1 = fmaf(q[1], s1, xm);
            s2 = fmaf(q[2], s2, xm);
            s3 = fmaf(q[3], s3, xm);
            acc[u] = fmaf(c[1], s1, c[0] * s0) + fmaf(c[3], s3, c[2] * s2);
        }
#pragma unroll
        for (int u = 0; u < 4; ++u) acc[u] += __shfl_xor(acc[u], 1);
#pragma unroll
        for (int u = 0; u < 4; ++u) acc[u] += __shfl_xor(acc[u], 2);
        if (ng == 0) {
#pragma unroll
            for (int u = 0; u < 4; ++u) {
                const int j = (DIR == 0) ? (jj + u) : (L - 1 - (jj + u));
                const size_t oi = (size_t)j * BD;
                if (DIR == 0) op[oi] = fmaf(xv[u], w, acc[u]);
                else { const float v = op[oi] + acc[u]; op[oi] = v / (1.0f + expf(-v)); }
            }
        }
    }
}

__global__ __launch_bounds__(64) void ema_fwd_kernel(
    const float* __restrict__ x, const float* __restrict__ damp,
    const float* __restrict__ decay, const float* __restrict__ ema,
    const float* __restrict__ proj, const float* __restrict__ rw,
    const int* __restrict__ mask, float* __restrict__ out)
{ ema_scan_body<0>(x, damp, decay, ema, proj, rw, mask, out); }

__global__ __launch_bounds__(64) void ema_bwd_kernel(
    const float* __restrict__ x, const float* __restrict__ damp,
    const float* __restrict__ decay, const float* __restrict__ ema,
    const float* __restrict__ proj, const float* __restrict__ rw,
    const int* __restrict__ mask, float* __restrict__ out)
{ ema_scan_body<1>(x, damp, decay, ema, proj, rw, mask, out); }

// ---------------- driver -----------------------------------------------------
extern "C" void kernel_launch(void* const* d_in, const int* in_sizes, int n_in,
                              void* d_out, int out_size, void* d_ws, size_t ws_size,
                              hipStream_t stream) {
    (void)in_sizes; (void)n_in; (void)out_size;
    const float* x     = (const float*)d_in[0];
    const float* damp  = (const float*)d_in[1];
    const float* decay = (const float*)d_in[2];
    const float* ema   = (const float*)d_in[3];
    const float* proj  = (const float*)d_in[4];
    const float* rw    = (const float*)d_in[5];
    const int*   mask  = (const int*)d_in[6];
    float* out = (float*)d_out;

    const size_t need = (size_t)2 * B * NC * D * ND * sizeof(float);  // 33.6 MB

    if (ws_size >= need) {
        float* fwdS = (float*)d_ws;
        float* bwdS = fwdS + (size_t)B * NC * D * ND;
        dim3 g(D / 64, B, NC);
        ema_summary_kernel<<<g, dim3(128), 0, stream>>>(x, damp, decay, mask, fwdS, bwdS);
        ema_prefix_kernel<<<dim3((B * D * ND) / 256), dim3(256), 0, stream>>>(damp, decay, fwdS, bwdS);
        ema_apply_kernel<<<g, dim3(128), 0, stream>>>(x, damp, decay, ema, proj, rw, mask,
                                                      fwdS, bwdS, out);
    } else {
        dim3 grid(D / 16, B);
        dim3 block(64);
        ema_fwd_kernel<<<grid, block, 0, stream>>>(x, damp, decay, ema, proj, rw, mask, out);
        ema_bwd_kernel<<<grid, block, 0, stream>>>(x, damp, decay, ema, proj, rw, mask, out);
    }
}

// Round 9
// 186.162 us; speedup vs baseline: 1.0893x; 1.0112x over previous
//
#include <hip/hip_runtime.h>
#include <math.h>

#define L 2048
#define B 8
#define D 1024
#define ND 16
#define BD (B*D)
#define CK 64                // chunk length
#define NC (L/CK)            // 32 chunks

typedef float v2f __attribute__((ext_vector_type(2)));

__device__ __forceinline__ float sigmoid_precise(float v) {
    return 1.0f / (1.0f + expf(-v));
}
// fast sigmoid: v_exp + v_rcp (~3e-7 rel err; tolerance is 0.0625 abs)
__device__ __forceinline__ float sigmoid_fast(float v) {
    return __builtin_amdgcn_rcpf(1.0f + __expf(-v));
}

// Per-mode decay packed as 8 x float2 (modes 2i,2i+1 in lanes .x/.y).
__device__ __forceinline__ void load_q2(const float* __restrict__ damp,
                                        const float* __restrict__ decay,
                                        int row, v2f* q2) {
#pragma unroll
    for (int mg = 0; mg < 4; ++mg) {
        const float4 dp = reinterpret_cast<const float4*>(damp)[row * 4 + mg];
        const float4 dc = reinterpret_cast<const float4*>(decay)[row * 4 + mg];
        const float qa = 1.f - sigmoid_fast(dp.x) * sigmoid_fast(dc.x);
        const float qb = 1.f - sigmoid_fast(dp.y) * sigmoid_fast(dc.y);
        const float qc = 1.f - sigmoid_fast(dp.z) * sigmoid_fast(dc.z);
        const float qd = 1.f - sigmoid_fast(dp.w) * sigmoid_fast(dc.w);
        q2[2*mg+0] = (v2f){qa, qb};
        q2[2*mg+1] = (v2f){qc, qd};
    }
}

// Packed decay q2[8] and output coefficient c2[8] (= p * ema * proj / sqrt(ND)).
__device__ __forceinline__ void load_qc2(const float* __restrict__ damp,
                                         const float* __restrict__ decay,
                                         const float* __restrict__ ema,
                                         const float* __restrict__ proj,
                                         int row, v2f* q2, v2f* c2) {
#pragma unroll
    for (int mg = 0; mg < 4; ++mg) {
        const float4 dp = reinterpret_cast<const float4*>(damp)[row * 4 + mg];
        const float4 dc = reinterpret_cast<const float4*>(decay)[row * 4 + mg];
        const float4 em = reinterpret_cast<const float4*>(ema)[row * 4 + mg];
        const float4 pj = reinterpret_cast<const float4*>(proj)[row * 4 + mg];
        const float p0 = sigmoid_fast(dp.x), p1 = sigmoid_fast(dp.y),
                    p2 = sigmoid_fast(dp.z), p3 = sigmoid_fast(dp.w);
        q2[2*mg+0] = (v2f){1.f - p0 * sigmoid_fast(dc.x), 1.f - p1 * sigmoid_fast(dc.y)};
        q2[2*mg+1] = (v2f){1.f - p2 * sigmoid_fast(dc.z), 1.f - p3 * sigmoid_fast(dc.w)};
        c2[2*mg+0] = (v2f){p0 * em.x * pj.x * 0.25f, p1 * em.y * pj.y * 0.25f};
        c2[2*mg+1] = (v2f){p2 * em.z * pj.z * 0.25f, p3 * em.w * pj.w * 0.25f};
    }
}

// ---------------- Phase A: per-chunk local states (both directions) ----------
// Block = 128 threads: wave 0 scans forward (u = i), wave 1 backward
// (u = i ^ (CK-1)). Software-pipelined 3-buffer prefetch (fully flattened,
// static register indexing only). Masks staged to LDS once per block.
// State math in packed float2 -> v_pk_fma_f32 (2 FMA / inst).
__global__ __launch_bounds__(128, 2) void ema_summary_kernel(
    const float* __restrict__ x, const float* __restrict__ damp,
    const float* __restrict__ decay, const int* __restrict__ mask,
    float* __restrict__ fwdS, float* __restrict__ bwdS)
{
    __shared__ float smask[CK];
    const int lane = threadIdx.x & 63;
    const int wid  = threadIdx.x >> 6;          // 0 = fwd, 1 = bwd
    const int d  = blockIdx.x * 64 + lane;
    const int b  = blockIdx.y;
    const int ch = blockIdx.z;
    const int j0 = ch * CK;
    const int um = wid ? (CK - 1) : 0;          // u = i ^ um

    const float* xp = x + (size_t)j0 * BD + (size_t)b * D + d;
    const int*   mp = mask + (size_t)b * L + j0;
    if (threadIdx.x < CK) smask[threadIdx.x] = (float)mp[threadIdx.x];
    __syncthreads();

    const int row = wid ? (d + D) : d;
    v2f q2[8], st2[8];
    load_q2(damp, decay, row, q2);
#pragma unroll
    for (int k = 0; k < 8; ++k) st2[k] = (v2f){0.f, 0.f};

    float xA[16], xB[16], xC[16];

#define SLOADG(XR, G) \
    _Pragma("unroll") \
    for (int v = 0; v < 16; ++v) { \
        const int u = ((G) + v) ^ um; \
        XR[v] = xp[(size_t)u * BD]; \
    }
#define SCOMPG(XR, G) \
    _Pragma("unroll") \
    for (int v = 0; v < 16; ++v) { \
        const int u = ((G) + v) ^ um; \
        const float xm = XR[v] * smask[u]; \
        const v2f xm2 = {xm, xm}; \
        _Pragma("unroll") \
        for (int k = 0; k < 8; ++k) st2[k] = q2[k] * st2[k] + xm2; \
    }

    SLOADG(xA, 0)
    SLOADG(xB, 16)
    SLOADG(xC, 32)
    SCOMPG(xA, 0)
    SLOADG(xA, 48)
    SCOMPG(xB, 16)
    SCOMPG(xC, 32)
    SCOMPG(xA, 48)
#undef SLOADG
#undef SCOMPG

    float* Sx = wid ? bwdS : fwdS;
    float4* s4 = reinterpret_cast<float4*>(Sx) + ((size_t)(b * NC + ch) * D + d) * 4;
#pragma unroll
    for (int mg = 0; mg < 4; ++mg)
        s4[mg] = make_float4(st2[2*mg+0].x, st2[2*mg+0].y, st2[2*mg+1].x, st2[2*mg+1].y);
}

// ---------------- Phase B: prefix across chunks (in-place -> entry states) ---
// One thread per (b, d, mode). All chunk values prefetched, then the two
// serial fma chains (fwd + bwd) interleaved for 2x chain ILP.
__global__ __launch_bounds__(256) void ema_prefix_kernel(
    const float* __restrict__ damp, const float* __restrict__ decay,
    float* __restrict__ fwdS, float* __restrict__ bwdS)
{
    const int tid = blockIdx.x * 256 + threadIdx.x;
    const int m = tid & (ND - 1);
    const int d = (tid >> 4) & (D - 1);
    const int b = tid >> 14;
    const size_t CS = (size_t)D * ND;   // stride between chunks
    const size_t off = (size_t)b * NC * CS + (size_t)d * ND + m;
    float* fb = fwdS + off;
    float* bb = bwdS + off;

    const int idxf = d * ND + m;
    const int idxb = (d + D) * ND + m;
    float qf = 1.f - sigmoid_fast(damp[idxf]) * sigmoid_fast(decay[idxf]);
    float qb = 1.f - sigmoid_fast(damp[idxb]) * sigmoid_fast(decay[idxb]);
#pragma unroll
    for (int s = 0; s < 6; ++s) { qf *= qf; qb *= qb; }   // q^64

    float Ef[NC], Eb[NC];
#pragma unroll
    for (int i = 0; i < NC; ++i) Ef[i] = fb[(size_t)i * CS];
#pragma unroll
    for (int i = 0; i < NC; ++i) Eb[i] = bb[(size_t)i * CS];

    float F = 0.f, G = 0.f;
#pragma unroll
    for (int i = 0; i < NC; ++i) {
        fb[(size_t)i * CS] = F;               F = fmaf(qf, F, Ef[i]);
        bb[(size_t)(NC-1-i) * CS] = G;        G = fmaf(qb, G, Eb[NC-1-i]);
    }
}

// ---------------- Phase C: apply (both directions + residual + silu) ---------
// Round-8 structure: half-LDS exchange + software-pipelined 3-buffer prefetch.
// Inner math in packed float2 (v_pk_fma_f32): 8 pk state-fma + 8 pk dot-fma
// per scan step instead of 32 scalar fma.
__global__ __launch_bounds__(128, 2) void ema_apply_kernel(
    const float* __restrict__ x, const float* __restrict__ damp,
    const float* __restrict__ decay, const float* __restrict__ ema,
    const float* __restrict__ proj, const float* __restrict__ rw,
    const int* __restrict__ mask,
    const float* __restrict__ fwdS, const float* __restrict__ bwdS,
    float* __restrict__ out)
{
    constexpr int HALF = CK / 2;
    __shared__ float hacc[2][HALF][64];      // 16 KB
    __shared__ float smask[CK];

    const int lane = threadIdx.x & 63;
    const int wid  = threadIdx.x >> 6;       // 0 = fwd, 1 = bwd
    const int d  = blockIdx.x * 64 + lane;
    const int b  = blockIdx.y;
    const int ch = blockIdx.z;
    const int j0 = ch * CK;
    const int um = wid ? (CK - 1) : 0;       // u = i ^ um

    const float* xp = x   + (size_t)j0 * BD + (size_t)b * D + d;
    float*       op = out + (size_t)j0 * BD + (size_t)b * D + d;
    const int*   mp = mask + (size_t)b * L + j0;
    if (threadIdx.x < CK) smask[threadIdx.x] = (float)mp[threadIdx.x];

    const int    row  = wid ? (d + D) : d;
    const float  weff = wid ? 0.f : rw[d];           // residual only on fwd wave
    const float* Sx   = wid ? bwdS : fwdS;

    v2f q2[8], c2[8], st2[8];
    load_qc2(damp, decay, ema, proj, row, q2, c2);
    {
        const float4* s4 = reinterpret_cast<const float4*>(Sx) + ((size_t)(b * NC + ch) * D + d) * 4;
#pragma unroll
        for (int mg = 0; mg < 4; ++mg) {
            const float4 v = s4[mg];
            st2[2*mg+0] = (v2f){v.x, v.y};
            st2[2*mg+1] = (v2f){v.z, v.w};
        }
    }
    __syncthreads();   // smask visible

    float xA[16], xB[16], xC[16];

#define ALOADG(XR, G) \
    _Pragma("unroll") \
    for (int v = 0; v < 16; ++v) { \
        const int u = ((G) + v) ^ um; \
        XR[v] = xp[(size_t)u * BD]; \
    }
#define ASTEP(XR, V, G) \
    const int u = ((G) + (V)) ^ um; \
    const float xraw = XR[V]; \
    const float xm   = xraw * smask[u]; \
    const v2f xm2 = {xm, xm}; \
    _Pragma("unroll") \
    for (int k = 0; k < 8; ++k) st2[k] = q2[k] * st2[k] + xm2; \
    v2f a0 = c2[0] * st2[0], a1 = c2[1] * st2[1], \
        a2 = c2[2] * st2[2], a3 = c2[3] * st2[3]; \
    a0 = c2[4] * st2[4] + a0; \
    a1 = c2[5] * st2[5] + a1; \
    a2 = c2[6] * st2[6] + a2; \
    a3 = c2[7] * st2[7] + a3; \
    const v2f sres = (a0 + a1) + (a2 + a3);
#define ACOMP_LDS(XR, G) \
    _Pragma("unroll") \
    for (int v = 0; v < 16; ++v) { \
        ASTEP(XR, v, G) \
        hacc[wid][u & (HALF - 1)][lane] = fmaf(xraw, weff, sres.x + sres.y); \
    }
#define ACOMP_OUT(XR, G) \
    _Pragma("unroll") \
    for (int v = 0; v < 16; ++v) { \
        ASTEP(XR, v, G) \
        const float tv  = fmaf(xraw, weff, sres.x + sres.y); \
        const float val = tv + hacc[ow][u & (HALF - 1)][lane]; \
        op[(size_t)u * BD] = val * __builtin_amdgcn_rcpf(1.0f + __expf(-val)); \
    }

    // phase 1 (scan steps 0..31 -> LDS), with phase-2 loads already in flight
    ALOADG(xA, 0)
    ALOADG(xB, 16)
    ALOADG(xC, 32)
    ACOMP_LDS(xA, 0)
    ALOADG(xA, 48)
    ACOMP_LDS(xB, 16)
    __syncthreads();

    // phase 2 (scan steps 32..63): combine with other wave's half, silu, store
    const int ow = 1 - wid;
    ACOMP_OUT(xC, 32)
    ACOMP_OUT(xA, 48)
#undef ALOADG
#undef ASTEP
#undef ACOMP_LDS
#undef ACOMP_OUT
}

// ---------------- Fallback: validated single-pass scans ----------------------
template<int DIR>
__device__ __forceinline__ void ema_scan_body(
    const float* __restrict__ x, const float* __restrict__ damp,
    const float* __restrict__ decay, const float* __restrict__ ema,
    const float* __restrict__ proj, const float* __restrict__ rw,
    const int* __restrict__ mask, float* __restrict__ out)
{
    const int t  = threadIdx.x;
    const int ng = t & 3;
    const int dl = t >> 2;
    const int d  = blockIdx.x * 16 + dl;
    const int b  = blockIdx.y;
    const int row = (DIR == 0) ? d : (d + D);

    float q[4], c[4];
#pragma unroll
    for (int k = 0; k < 4; ++k) {
        const int idx = row * ND + ng * 4 + k;
        const float p  = sigmoid_precise(damp[idx]);
        const float sd = sigmoid_precise(decay[idx]);
        q[k] = 1.0f - p * sd;
        c[k] = p * ema[idx] * proj[idx] * 0.25f;
    }
    const float w = rw[d];
    const float* xp = x + (size_t)b * D + d;
    float*       op = out + (size_t)b * D + d;
    const int*   mp = mask + (size_t)b * L;
    float s0 = 0.f, s1 = 0.f, s2 = 0.f, s3 = 0.f;

    for (int jj = 0; jj < L; jj += 4) {
        float xv[4], mf[4];
#pragma unroll
        for (int u = 0; u < 4; ++u) {
            const int j = (DIR == 0) ? (jj + u) : (L - 1 - (jj + u));
            xv[u] = xp[(size_t)j * BD];
            mf[u] = (float)mp[j];
        }
        float acc[4];
#pragma unroll
        for (int u = 0; u < 4; ++u) {
            const float xm = xv[u] * mf[u];
            s0 = fmaf(q[0], s0, xm);
            s1 = fmaf(q[1], s1, xm);
            s2 = fmaf(q[2], s2, xm);
            s3 = fmaf(q[3], s3, xm);
            acc[u] = fmaf(c[1], s1, c[0] * s0) + fmaf(c[3], s3, c[2] * s2);
        }
#pragma unroll
        for (int u = 0; u < 4; ++u) acc[u] += __shfl_xor(acc[u], 1);
#pragma unroll
        for (int u = 0; u < 4; ++u) acc[u] += __shfl_xor(acc[u], 2);
        if (ng == 0) {
#pragma unroll
            for (int u = 0; u < 4; ++u) {
                const int j = (DIR == 0) ? (jj + u) : (L - 1 - (jj + u));
                const size_t oi = (size_t)j * BD;
                if (DIR == 0) op[oi] = fmaf(xv[u], w, acc[u]);
                else { const float v = op[oi] + acc[u]; op[oi] = v / (1.0f + expf(-v)); }
            }
        }
    }
}

__global__ __launch_bounds__(64) void ema_fwd_kernel(
    const float* __restrict__ x, const float* __restrict__ damp,
    const float* __restrict__ decay, const float* __restrict__ ema,
    const float* __restrict__ proj, const float* __restrict__ rw,
    const int* __restrict__ mask, float* __restrict__ out)
{ ema_scan_body<0>(x, damp, decay, ema, proj, rw, mask, out); }

__global__ __launch_bounds__(64) void ema_bwd_kernel(
    const float* __restrict__ x, const float* __restrict__ damp,
    const float* __restrict__ decay, const float* __restrict__ ema,
    const float* __restrict__ proj, const float* __restrict__ rw,
    const int* __restrict__ mask, float* __restrict__ out)
{ ema_scan_body<1>(x, damp, decay, ema, proj, rw, mask, out); }

// ---------------- driver -----------------------------------------------------
extern "C" void kernel_launch(void* const* d_in, const int* in_sizes, int n_in,
                              void* d_out, int out_size, void* d_ws, size_t ws_size,
                              hipStream_t stream) {
    (void)in_sizes; (void)n_in; (void)out_size;
    const float* x     = (const float*)d_in[0];
    const float* damp  = (const float*)d_in[1];
    const float* decay = (const float*)d_in[2];
    const float* ema   = (const float*)d_in[3];
    const float* proj  = (const float*)d_in[4];
    const float* rw    = (const float*)d_in[5];
    const int*   mask  = (const int*)d_in[6];
    float* out = (float*)d_out;

    const size_t need = (size_t)2 * B * NC * D * ND * sizeof(float);  // 33.6 MB

    if (ws_size >= need) {
        float* fwdS = (float*)d_ws;
        float* bwdS = fwdS + (size_t)B * NC * D * ND;
        dim3 g(D / 64, B, NC);
        ema_summary_kernel<<<g, dim3(128), 0, stream>>>(x, damp, decay, mask, fwdS, bwdS);
        ema_prefix_kernel<<<dim3((B * D * ND) / 256), dim3(256), 0, stream>>>(damp, decay, fwdS, bwdS);
        ema_apply_kernel<<<g, dim3(128), 0, stream>>>(x, damp, decay, ema, proj, rw, mask,
                                                      fwdS, bwdS, out);
    } else {
        dim3 grid(D / 16, B);
        dim3 block(64);
        ema_fwd_kernel<<<grid, block, 0, stream>>>(x, damp, decay, ema, proj, rw, mask, out);
        ema_bwd_kernel<<<grid, block, 0, stream>>>(x, damp, decay, ema, proj, rw, mask, out);
    }
}